// Round 8
// baseline (298.873 us; speedup 1.0000x reference)
//
#include <hip/hip_runtime.h>
#include <hip/hip_cooperative_groups.h>

namespace cg = cooperative_groups;

#define FEAT 512
#define FEAT4 128          // FEAT / 4
#define NGRAPH 512
#define NBC 1024           // cooperative grid: 4 blocks/CU x 256 CU, co-resident
#define NBF 2048           // fallback two-kernel grid
#define MAXSLOT 8          // max blocks one graph can span
#define EPS 1e-7f

typedef float f32x4 __attribute__((ext_vector_type(4)));

__device__ __forceinline__ void acc4(float4& s, const float4 v) {
    s.x += v.x; s.y += v.y; s.z += v.z; s.w += v.w;
}
__device__ __forceinline__ void accsq4(float4& s, const float4 v) {
    s.x += v.x * v.x; s.y += v.y * v.y; s.z += v.z * v.z; s.w += v.w * v.w;
}
__device__ __forceinline__ float4 add4(const float4 a, const float4 b) {
    return make_float4(a.x + b.x, a.y + b.y, a.z + b.z, a.w + b.w);
}
// XCD-chunked bijection (nb % 8 == 0): row-neighbor blocks share an XCD L2.
__device__ __forceinline__ int logical_block(int pb, int nb) {
    return (pb & 7) * (nb >> 3) + (pb >> 3);
}

// ---------------------------------------------------------------------------
// K0: segment-boundary table. SEGSTART[g] = lower_bound(map, g); SEGSTART[G]=n.
// ---------------------------------------------------------------------------
__global__ __launch_bounds__(256) void gn_bounds(
    const int* __restrict__ map, int* __restrict__ segstart, int n_nodes)
{
    const int i = blockIdx.x * blockDim.x + threadIdx.x;
    if (i >= n_nodes) return;
    const int cur  = map[i];
    const int prev = (i == 0) ? -1 : map[i - 1];
    for (int g = prev + 1; g <= cur; ++g) segstart[g] = i;
    if (i == n_nodes - 1)
        for (int g = cur + 1; g <= NGRAPH; ++g) segstart[g] = n_nodes;
}

// ---------------------------------------------------------------------------
// Cooperative fused kernel. Block lb owns rows [lb*rpb,(lb+1)*rpb).
// Phase 1: stream slab, publish per-(graph,slot) raw moments to PPART.
// grid.sync() (one global barrier; threadfence makes partials MALL-visible
// across XCDs).
// Phase 2: per segment gather <=MAXSLOT partials (L2/MALL-hot), finalize
//   s,t in registers, re-read slab (MALL-hit: feat stayed resident, proven
//   by R5's FETCH=199MB) and write out = h*s + t with NT stores.
// var(h-a*mu) = E[h^2] - mu^2*(2a-a^2); s = gamma/(sqrt(var)+eps);
// t = beta - a*mu*s.
// NOTE: inactive tail blocks must still reach grid.sync().
// ---------------------------------------------------------------------------
__global__ __launch_bounds__(256, 4) void gn_coop(
    const float* __restrict__ feat,
    const int*   __restrict__ map,
    const int*   __restrict__ segstart,
    float*       __restrict__ PPART,   // [NGRAPH][MAXSLOT][2][FEAT]
    const float* __restrict__ alpha,
    const float* __restrict__ beta,
    const float* __restrict__ gamma,
    float*       __restrict__ out,
    int n_nodes, int rpb)
{
    cg::grid_group grid = cg::this_grid();

    const int lb = logical_block(blockIdx.x, gridDim.x);
    const int rs = lb * rpb;
    const int re = min(rs + rpb, n_nodes);
    const bool active = (rs < n_nodes);

    const int tid = threadIdx.x;
    const int q = tid & (FEAT4 - 1);
    const int r = tid >> 7;

    __shared__ float4 lsum[2][FEAT4];   // 4 KB
    __shared__ float4 lssq[2][FEAT4];   // 4 KB

    const float4* __restrict__ f4 = (const float4*)feat;
    float4* __restrict__ P4 = (float4*)PPART;

    // ---------------- phase 1: publish partials ----------------
    if (active) {
        int cur = rs;
        int g = map[rs];
        int slot = lb - segstart[g] / rpb;
        while (cur < re) {
            const int send = min(segstart[g + 1], re);

            float4 sum = make_float4(0.f, 0.f, 0.f, 0.f);
            float4 ssq = make_float4(0.f, 0.f, 0.f, 0.f);
            #pragma unroll 4
            for (int row = cur + r; row < send; row += 2) {
                float4 v = f4[(size_t)row * FEAT4 + q];
                acc4(sum, v);
                accsq4(ssq, v);
            }
            lsum[r][q] = sum;
            lssq[r][q] = ssq;
            __syncthreads();
            if (r == 0 && slot >= 0 && slot < MAXSLOT) {
                const size_t o = ((size_t)(g * MAXSLOT + slot) * 2) * FEAT4 + q;
                P4[o]         = add4(lsum[0][q], lsum[1][q]);
                P4[o + FEAT4] = add4(lssq[0][q], lssq[1][q]);
            }
            __syncthreads();
            cur = send;
            if (cur < re) g = map[cur];
            slot = 0;
        }
    }

    __threadfence();   // device-scope release: partials -> MALL before barrier
    grid.sync();

    // ---------------- phase 2: finalize + apply ----------------
    if (active) {
        const float4 al = ((const float4*)alpha)[q];
        const float4 be = ((const float4*)beta)[q];
        const float4 ga = ((const float4*)gamma)[q];
        f32x4* __restrict__ o4 = (f32x4*)out;

        int cur = rs;
        int g = map[rs];
        while (cur < re) {
            const int gstart = segstart[g];
            const int gend   = segstart[g + 1];
            const int send   = min(gend, re);
            const int cnt    = gend - gstart;
            const int bfirst = gstart / rpb;
            int nslots = (gend - 1) / rpb - bfirst + 1;
            if (nslots > MAXSLOT) nslots = MAXSLOT;

            float4 sum = make_float4(0.f, 0.f, 0.f, 0.f);
            float4 ssq = make_float4(0.f, 0.f, 0.f, 0.f);
            for (int s = 0; s < nslots; ++s) {
                const size_t o = ((size_t)(g * MAXSLOT + s) * 2) * FEAT4 + q;
                acc4(sum, P4[o]);
                acc4(ssq, P4[o + FEAT4]);
            }

            const float inv = 1.0f / (float)max(cnt, 1);
            f32x4 sv, tv;
            {
                const float mu[4]  = { sum.x * inv, sum.y * inv, sum.z * inv, sum.w * inv };
                const float msq[4] = { ssq.x * inv, ssq.y * inv, ssq.z * inv, ssq.w * inv };
                const float aa[4]  = { al.x, al.y, al.z, al.w };
                const float bb[4]  = { be.x, be.y, be.z, be.w };
                const float gg[4]  = { ga.x, ga.y, ga.z, ga.w };
                #pragma unroll
                for (int j = 0; j < 4; ++j) {
                    float var = msq[j] - mu[j] * mu[j] * (2.0f * aa[j] - aa[j] * aa[j]);
                    var = fmaxf(var, 0.0f);
                    const float s = gg[j] / (sqrtf(var) + EPS);
                    sv[j] = s;
                    tv[j] = bb[j] - aa[j] * mu[j] * s;
                }
            }

            const f32x4* __restrict__ f4n = (const f32x4*)feat;
            #pragma unroll 4
            for (int row = cur + r; row < send; row += 2) {
                const size_t idx = (size_t)row * FEAT4 + q;
                f32x4 v = *(const f32x4*)&f4n[idx];   // plain load: hit MALL
                f32x4 o = v * sv + tv;
                __builtin_nontemporal_store(o, &o4[idx]);
            }
            cur = send;
            if (cur < re) g = map[cur];
        }
    }
}

// ---------------------------------------------------------------------------
// Fallback path: R7's proven two-kernel pipeline (111 us).
// ---------------------------------------------------------------------------
__global__ __launch_bounds__(256) void gn_partial(
    const float* __restrict__ feat,
    const int*   __restrict__ map,
    const int*   __restrict__ segstart,
    float*       __restrict__ PPART,
    int n_nodes, int rpb)
{
    const int lb = logical_block(blockIdx.x, gridDim.x);
    const int rs = lb * rpb;
    if (rs >= n_nodes) return;
    const int re = min(rs + rpb, n_nodes);

    const int tid = threadIdx.x;
    const int q = tid & (FEAT4 - 1);
    const int r = tid >> 7;

    __shared__ float4 lsum[2][FEAT4];
    __shared__ float4 lssq[2][FEAT4];
    const float4* __restrict__ f4 = (const float4*)feat;
    float4* __restrict__ P4 = (float4*)PPART;

    int cur = rs;
    int g = map[rs];
    int slot = lb - segstart[g] / rpb;
    while (cur < re) {
        const int send = min(segstart[g + 1], re);

        float4 sum = make_float4(0.f, 0.f, 0.f, 0.f);
        float4 ssq = make_float4(0.f, 0.f, 0.f, 0.f);
        #pragma unroll 4
        for (int row = cur + r; row < send; row += 2) {
            float4 v = f4[(size_t)row * FEAT4 + q];
            acc4(sum, v);
            accsq4(ssq, v);
        }
        lsum[r][q] = sum;
        lssq[r][q] = ssq;
        __syncthreads();
        if (r == 0 && slot >= 0 && slot < MAXSLOT) {
            const size_t o = ((size_t)(g * MAXSLOT + slot) * 2) * FEAT4 + q;
            P4[o]         = add4(lsum[0][q], lsum[1][q]);
            P4[o + FEAT4] = add4(lssq[0][q], lssq[1][q]);
        }
        __syncthreads();
        cur = send;
        if (cur < re) g = map[cur];
        slot = 0;
    }
}

__global__ __launch_bounds__(256) void gn_apply(
    const float* __restrict__ feat,
    const int*   __restrict__ map,
    const int*   __restrict__ segstart,
    const float* __restrict__ PPART,
    const float* __restrict__ alpha,
    const float* __restrict__ beta,
    const float* __restrict__ gamma,
    float*       __restrict__ out,
    int n_nodes, int rpb)
{
    const int lb = logical_block(blockIdx.x, gridDim.x);
    const int rs = lb * rpb;
    if (rs >= n_nodes) return;
    const int re = min(rs + rpb, n_nodes);

    const int tid = threadIdx.x;
    const int q = tid & (FEAT4 - 1);
    const int r = tid >> 7;

    const f32x4* __restrict__ f4n = (const f32x4*)feat;
    const float4* __restrict__ P4 = (const float4*)PPART;
    f32x4* __restrict__ o4 = (f32x4*)out;

    const float4 al = ((const float4*)alpha)[q];
    const float4 be = ((const float4*)beta)[q];
    const float4 ga = ((const float4*)gamma)[q];

    int cur = rs;
    int g = map[rs];
    while (cur < re) {
        const int gstart = segstart[g];
        const int gend   = segstart[g + 1];
        const int send   = min(gend, re);
        const int cnt    = gend - gstart;
        const int bfirst = gstart / rpb;
        int nslots = (gend - 1) / rpb - bfirst + 1;
        if (nslots > MAXSLOT) nslots = MAXSLOT;

        float4 sum = make_float4(0.f, 0.f, 0.f, 0.f);
        float4 ssq = make_float4(0.f, 0.f, 0.f, 0.f);
        for (int s = 0; s < nslots; ++s) {
            const size_t o = ((size_t)(g * MAXSLOT + s) * 2) * FEAT4 + q;
            acc4(sum, P4[o]);
            acc4(ssq, P4[o + FEAT4]);
        }

        const float inv = 1.0f / (float)max(cnt, 1);
        f32x4 sv, tv;
        {
            const float mu[4]  = { sum.x * inv, sum.y * inv, sum.z * inv, sum.w * inv };
            const float msq[4] = { ssq.x * inv, ssq.y * inv, ssq.z * inv, ssq.w * inv };
            const float aa[4]  = { al.x, al.y, al.z, al.w };
            const float bb[4]  = { be.x, be.y, be.z, be.w };
            const float gg[4]  = { ga.x, ga.y, ga.z, ga.w };
            #pragma unroll
            for (int j = 0; j < 4; ++j) {
                float var = msq[j] - mu[j] * mu[j] * (2.0f * aa[j] - aa[j] * aa[j]);
                var = fmaxf(var, 0.0f);
                const float s = gg[j] / (sqrtf(var) + EPS);
                sv[j] = s;
                tv[j] = bb[j] - aa[j] * mu[j] * s;
            }
        }

        #pragma unroll 4
        for (int row = cur + r; row < send; row += 2) {
            const size_t idx = (size_t)row * FEAT4 + q;
            f32x4 v = __builtin_nontemporal_load(&f4n[idx]);
            f32x4 o = v * sv + tv;
            __builtin_nontemporal_store(o, &o4[idx]);
        }
        cur = send;
        if (cur < re) g = map[cur];
    }
}

extern "C" void kernel_launch(void* const* d_in, const int* in_sizes, int n_in,
                              void* d_out, int out_size, void* d_ws, size_t ws_size,
                              hipStream_t stream) {
    const float* feat  = (const float*)d_in[0];
    const int*   map   = (const int*)d_in[1];
    const float* alpha = (const float*)d_in[2];
    const float* beta  = (const float*)d_in[3];
    const float* gamma = (const float*)d_in[4];
    float* outp = (float*)d_out;

    int n_nodes = in_sizes[1];

    const size_t ppartElems = (size_t)NGRAPH * MAXSLOT * 2 * FEAT;   // 4.19M floats
    float* PPART    = (float*)d_ws;
    int*   SEGSTART = (int*)((float*)d_ws + ppartElems);

    const int bblocks = (n_nodes + 255) / 256;
    gn_bounds<<<bblocks, 256, 0, stream>>>(map, SEGSTART, n_nodes);

    int rpb = (n_nodes + NBC - 1) / NBC;
    void* args[] = { (void*)&feat, (void*)&map, (void*)&SEGSTART, (void*)&PPART,
                     (void*)&alpha, (void*)&beta, (void*)&gamma, (void*)&outp,
                     (void*)&n_nodes, (void*)&rpb };
    hipError_t err = hipLaunchCooperativeKernel((const void*)gn_coop,
                                                dim3(NBC), dim3(256),
                                                args, 0, stream);
    if (err != hipSuccess) {
        // fallback: proven two-kernel pipeline
        const int rpb2 = (n_nodes + NBF - 1) / NBF;
        gn_partial<<<NBF, 256, 0, stream>>>(feat, map, SEGSTART, PPART, n_nodes, rpb2);
        gn_apply<<<NBF, 256, 0, stream>>>(feat, map, SEGSTART, PPART,
                                          alpha, beta, gamma, outp, n_nodes, rpb2);
    }
}

// Round 9
// 123.563 us; speedup vs baseline: 2.4188x; 2.4188x over previous
//
#include <hip/hip_runtime.h>

#define FEAT 512
#define FEAT4 128          // FEAT / 4
#define NGRAPH 512
#define NB 2048            // row-partition blocks (rpb = 49 @ N=100000)
#define MAXSLOT 8          // max blocks one graph can span (cnt<=260 << 8*49)
#define EPS 1e-7f

typedef float f32x4 __attribute__((ext_vector_type(4)));

__device__ __forceinline__ void acc4(float4& s, const float4 v) {
    s.x += v.x; s.y += v.y; s.z += v.z; s.w += v.w;
}
__device__ __forceinline__ void accsq4(float4& s, const float4 v) {
    s.x += v.x * v.x; s.y += v.y * v.y; s.z += v.z * v.z; s.w += v.w * v.w;
}
__device__ __forceinline__ float4 add4(const float4 a, const float4 b) {
    return make_float4(a.x + b.x, a.y + b.y, a.z + b.z, a.w + b.w);
}
// XCD-chunked bijection (nb % 8 == 0): row-neighbor blocks share an XCD L2.
__device__ __forceinline__ int logical_block(int pb, int nb) {
    return (pb & 7) * (nb >> 3) + (pb >> 3);
}

// ---------------------------------------------------------------------------
// K0: segment-boundary table. SEGSTART[g] = lower_bound(map, g); SEGSTART[G]=n.
// ---------------------------------------------------------------------------
__global__ __launch_bounds__(256) void gn_bounds(
    const int* __restrict__ map, int* __restrict__ segstart, int n_nodes)
{
    const int i = blockIdx.x * blockDim.x + threadIdx.x;
    if (i >= n_nodes) return;
    const int cur  = map[i];
    const int prev = (i == 0) ? -1 : map[i - 1];
    for (int g = prev + 1; g <= cur; ++g) segstart[g] = i;
    if (i == n_nodes - 1)
        for (int g = cur + 1; g <= NGRAPH; ++g) segstart[g] = n_nodes;
}

// ---------------------------------------------------------------------------
// K1: uniform row partition -> per-(graph, slot) raw moments.
// Plain loads (feat must allocate in MALL: K2 re-reads it).
// ---------------------------------------------------------------------------
__global__ __launch_bounds__(256) void gn_partial(
    const float* __restrict__ feat,
    const int*   __restrict__ map,
    const int*   __restrict__ segstart,
    float*       __restrict__ PPART,
    int n_nodes, int rpb)
{
    const int lb = logical_block(blockIdx.x, gridDim.x);
    const int rs = lb * rpb;
    if (rs >= n_nodes) return;
    const int re = min(rs + rpb, n_nodes);

    const int tid = threadIdx.x;
    const int q = tid & (FEAT4 - 1);
    const int r = tid >> 7;

    __shared__ float4 lsum[2][FEAT4];
    __shared__ float4 lssq[2][FEAT4];
    const float4* __restrict__ f4 = (const float4*)feat;
    float4* __restrict__ P4 = (float4*)PPART;

    int cur = rs;
    int g = map[rs];
    int slot = lb - segstart[g] / rpb;
    while (cur < re) {
        const int send = min(segstart[g + 1], re);

        float4 sum = make_float4(0.f, 0.f, 0.f, 0.f);
        float4 ssq = make_float4(0.f, 0.f, 0.f, 0.f);
        #pragma unroll 8
        for (int row = cur + r; row < send; row += 2) {
            float4 v = f4[(size_t)row * FEAT4 + q];
            acc4(sum, v);
            accsq4(ssq, v);
        }
        lsum[r][q] = sum;
        lssq[r][q] = ssq;
        __syncthreads();
        if (r == 0 && slot >= 0 && slot < MAXSLOT) {
            const size_t o = ((size_t)(g * MAXSLOT + slot) * 2) * FEAT4 + q;
            P4[o]         = add4(lsum[0][q], lsum[1][q]);
            P4[o + FEAT4] = add4(lssq[0][q], lssq[1][q]);
        }
        __syncthreads();
        cur = send;
        if (cur < re) g = map[cur];
        slot = 0;   // later segments start inside this window
    }
}

// ---------------------------------------------------------------------------
// K2: fused finalize + apply. Per segment: gather <=MAXSLOT partials
// (L2/MALL-hot), finalize s,t in registers:
//   var(h-a*mu) = E[h^2] - mu^2*(2a-a^2); s = gamma/(sqrt(var)+eps);
//   t = beta - a*mu*s;  out = h*s + t.
// PLAIN loads (hit MALL lines K1 allocated) and PLAIN stores (A/B vs NT:
// session evidence suggests NT stores cost ~5us; eviction of already-read
// feat lines is harmless since each line is read exactly once here).
// ---------------------------------------------------------------------------
__global__ __launch_bounds__(256) void gn_apply(
    const float* __restrict__ feat,
    const int*   __restrict__ map,
    const int*   __restrict__ segstart,
    const float* __restrict__ PPART,
    const float* __restrict__ alpha,
    const float* __restrict__ beta,
    const float* __restrict__ gamma,
    float*       __restrict__ out,
    int n_nodes, int rpb)
{
    const int lb = logical_block(blockIdx.x, gridDim.x);
    const int rs = lb * rpb;
    if (rs >= n_nodes) return;
    const int re = min(rs + rpb, n_nodes);

    const int tid = threadIdx.x;
    const int q = tid & (FEAT4 - 1);
    const int r = tid >> 7;

    const f32x4* __restrict__ f4n = (const f32x4*)feat;
    const float4* __restrict__ P4 = (const float4*)PPART;
    f32x4* __restrict__ o4 = (f32x4*)out;

    const float4 al = ((const float4*)alpha)[q];
    const float4 be = ((const float4*)beta)[q];
    const float4 ga = ((const float4*)gamma)[q];

    int cur = rs;
    int g = map[rs];
    while (cur < re) {
        const int gstart = segstart[g];
        const int gend   = segstart[g + 1];
        const int send   = min(gend, re);
        const int cnt    = gend - gstart;
        const int bfirst = gstart / rpb;
        int nslots = (gend - 1) / rpb - bfirst + 1;
        if (nslots > MAXSLOT) nslots = MAXSLOT;

        float4 sum = make_float4(0.f, 0.f, 0.f, 0.f);
        float4 ssq = make_float4(0.f, 0.f, 0.f, 0.f);
        for (int s = 0; s < nslots; ++s) {
            const size_t o = ((size_t)(g * MAXSLOT + s) * 2) * FEAT4 + q;
            acc4(sum, P4[o]);
            acc4(ssq, P4[o + FEAT4]);
        }

        const float inv = 1.0f / (float)max(cnt, 1);
        f32x4 sv, tv;
        {
            const float mu[4]  = { sum.x * inv, sum.y * inv, sum.z * inv, sum.w * inv };
            const float msq[4] = { ssq.x * inv, ssq.y * inv, ssq.z * inv, ssq.w * inv };
            const float aa[4]  = { al.x, al.y, al.z, al.w };
            const float bb[4]  = { be.x, be.y, be.z, be.w };
            const float gg[4]  = { ga.x, ga.y, ga.z, ga.w };
            #pragma unroll
            for (int j = 0; j < 4; ++j) {
                float var = msq[j] - mu[j] * mu[j] * (2.0f * aa[j] - aa[j] * aa[j]);
                var = fmaxf(var, 0.0f);
                const float s = gg[j] / (sqrtf(var) + EPS);
                sv[j] = s;
                tv[j] = bb[j] - aa[j] * mu[j] * s;
            }
        }

        #pragma unroll 8
        for (int row = cur + r; row < send; row += 2) {
            const size_t idx = (size_t)row * FEAT4 + q;
            f32x4 v = f4n[idx];          // plain load: hit MALL
            f32x4 o = v * sv + tv;
            o4[idx] = o;                 // plain store
        }
        cur = send;
        if (cur < re) g = map[cur];
    }
}

// ---------------------------------------------------------------------------
// Small-workspace fallback (R1 proven path; needs only ~2 MB). Never expected
// to trigger (ws ~800 MB observed), kept as a safety net.
// ---------------------------------------------------------------------------
__global__ __launch_bounds__(512) void graphnorm_stats(
    const float* __restrict__ feat,
    const int*   __restrict__ map,
    const float* __restrict__ alpha,
    const float* __restrict__ beta,
    const float* __restrict__ gamma,
    float* __restrict__ S,
    float* __restrict__ T,
    int n_nodes)
{
    const int g = blockIdx.x;
    int lo = 0, hi = n_nodes;
    while (lo < hi) { int mid = (lo + hi) >> 1; if (map[mid] < g) lo = mid + 1; else hi = mid; }
    const int seg_start = lo;
    hi = n_nodes;
    while (lo < hi) { int mid = (lo + hi) >> 1; if (map[mid] < g + 1) lo = mid + 1; else hi = mid; }
    const int seg_end = lo;
    const int cnt = seg_end - seg_start;

    const int tid = threadIdx.x;
    const int q = tid & (FEAT4 - 1);
    const int r = tid >> 7;

    float4 sum = make_float4(0.f, 0.f, 0.f, 0.f);
    float4 ssq = make_float4(0.f, 0.f, 0.f, 0.f);
    const float4* __restrict__ f4 = (const float4*)feat;

    for (int row = seg_start + r; row < seg_end; row += 4) {
        float4 v = f4[(size_t)row * FEAT4 + q];
        acc4(sum, v);
        accsq4(ssq, v);
    }

    __shared__ float4 lsum[4][FEAT4];
    __shared__ float4 lssq[4][FEAT4];
    lsum[r][q] = sum;
    lssq[r][q] = ssq;
    __syncthreads();

    if (r == 0) {
        #pragma unroll
        for (int k = 1; k < 4; ++k) {
            acc4(sum, lsum[k][q]);
            acc4(ssq, lssq[k][q]);
        }
        const float inv = 1.0f / (float)max(cnt, 1);
        float4 al = ((const float4*)alpha)[q];
        float4 be = ((const float4*)beta)[q];
        float4 ga = ((const float4*)gamma)[q];
        float mu[4]  = { sum.x * inv, sum.y * inv, sum.z * inv, sum.w * inv };
        float msq[4] = { ssq.x * inv, ssq.y * inv, ssq.z * inv, ssq.w * inv };
        float a[4]   = { al.x, al.y, al.z, al.w };
        float bb[4]  = { be.x, be.y, be.z, be.w };
        float gg[4]  = { ga.x, ga.y, ga.z, ga.w };
        float so[4], to[4];
        #pragma unroll
        for (int j = 0; j < 4; ++j) {
            float var = msq[j] - mu[j] * mu[j] * (2.0f * a[j] - a[j] * a[j]);
            var = fmaxf(var, 0.0f);
            float s = gg[j] / (sqrtf(var) + EPS);
            so[j] = s;
            to[j] = bb[j] - a[j] * mu[j] * s;
        }
        ((float4*)S)[(size_t)g * FEAT4 + q] = make_float4(so[0], so[1], so[2], so[3]);
        ((float4*)T)[(size_t)g * FEAT4 + q] = make_float4(to[0], to[1], to[2], to[3]);
    }
}

__global__ __launch_bounds__(256) void graphnorm_apply_tab(
    const float* __restrict__ feat,
    const int*   __restrict__ map,
    const float* __restrict__ S,
    const float* __restrict__ T,
    float* __restrict__ out,
    long total4)
{
    const float4* __restrict__ f4 = (const float4*)feat;
    const float4* __restrict__ S4 = (const float4*)S;
    const float4* __restrict__ T4 = (const float4*)T;
    f32x4* __restrict__ o4 = (f32x4*)out;

    const long stride = (long)gridDim.x * blockDim.x;
    for (long idx = (long)blockIdx.x * blockDim.x + threadIdx.x; idx < total4; idx += stride) {
        const int n = (int)(idx >> 7);
        const int q = (int)(idx & (FEAT4 - 1));
        const int g = map[n];
        float4 v = f4[idx];
        float4 s = S4[(size_t)g * FEAT4 + q];
        float4 t = T4[(size_t)g * FEAT4 + q];
        f32x4 o;
        o.x = v.x * s.x + t.x;
        o.y = v.y * s.y + t.y;
        o.z = v.z * s.z + t.z;
        o.w = v.w * s.w + t.w;
        o4[idx] = o;
    }
}

extern "C" void kernel_launch(void* const* d_in, const int* in_sizes, int n_in,
                              void* d_out, int out_size, void* d_ws, size_t ws_size,
                              hipStream_t stream) {
    const float* feat  = (const float*)d_in[0];
    const int*   map   = (const int*)d_in[1];
    const float* alpha = (const float*)d_in[2];
    const float* beta  = (const float*)d_in[3];
    const float* gamma = (const float*)d_in[4];

    const int n_nodes = in_sizes[1];
    const int rpb = (n_nodes + NB - 1) / NB;

    const size_t ppartElems = (size_t)NGRAPH * MAXSLOT * 2 * FEAT;   // 4.19M floats
    const size_t needBytes  = ppartElems * 4 + (NGRAPH + 1) * sizeof(int); // ~16.8 MB

    if (ws_size >= needBytes) {
        float* PPART    = (float*)d_ws;
        int*   SEGSTART = (int*)((float*)d_ws + ppartElems);

        const int bblocks = (n_nodes + 255) / 256;
        gn_bounds<<<bblocks, 256, 0, stream>>>(map, SEGSTART, n_nodes);
        gn_partial<<<NB, 256, 0, stream>>>(feat, map, SEGSTART, PPART, n_nodes, rpb);
        gn_apply<<<NB, 256, 0, stream>>>(feat, map, SEGSTART, PPART,
                                         alpha, beta, gamma,
                                         (float*)d_out, n_nodes, rpb);
    } else {
        float* S = (float*)d_ws;
        float* T = S + (size_t)NGRAPH * FEAT;
        graphnorm_stats<<<NGRAPH, 512, 0, stream>>>(feat, map, alpha, beta, gamma, S, T, n_nodes);
        const long total4 = (long)n_nodes * FEAT4;
        graphnorm_apply_tab<<<2048, 256, 0, stream>>>(feat, map, S, T, (float*)d_out, total4);
    }
}

// Round 10
// 114.625 us; speedup vs baseline: 2.6074x; 1.0780x over previous
//
#include <hip/hip_runtime.h>

#define FEAT 512
#define FEAT4 128          // FEAT / 4
#define NGRAPH 512
#define NB 2048            // row-partition blocks (rpb = 49 @ N=100000)
#define MAXSLOT 8          // max blocks one graph can span (cnt<=260 << 8*49)
#define EPS 1e-7f

typedef float f32x4 __attribute__((ext_vector_type(4)));

__device__ __forceinline__ void acc4(float4& s, const float4 v) {
    s.x += v.x; s.y += v.y; s.z += v.z; s.w += v.w;
}
__device__ __forceinline__ void accsq4(float4& s, const float4 v) {
    s.x += v.x * v.x; s.y += v.y * v.y; s.z += v.z * v.z; s.w += v.w * v.w;
}
__device__ __forceinline__ float4 add4(const float4 a, const float4 b) {
    return make_float4(a.x + b.x, a.y + b.y, a.z + b.z, a.w + b.w);
}
// XCD-chunked bijection (nb % 8 == 0): row-neighbor blocks share an XCD L2.
__device__ __forceinline__ int logical_block(int pb, int nb) {
    return (pb & 7) * (nb >> 3) + (pb >> 3);
}

// ---------------------------------------------------------------------------
// K0: segment-boundary table. SEGSTART[g] = lower_bound(map, g); SEGSTART[G]=n.
// ---------------------------------------------------------------------------
__global__ __launch_bounds__(256) void gn_bounds(
    const int* __restrict__ map, int* __restrict__ segstart, int n_nodes)
{
    const int i = blockIdx.x * blockDim.x + threadIdx.x;
    if (i >= n_nodes) return;
    const int cur  = map[i];
    const int prev = (i == 0) ? -1 : map[i - 1];
    for (int g = prev + 1; g <= cur; ++g) segstart[g] = i;
    if (i == n_nodes - 1)
        for (int g = cur + 1; g <= NGRAPH; ++g) segstart[g] = n_nodes;
}

// ---------------------------------------------------------------------------
// K1: uniform row partition -> per-(graph, slot) raw moments.
// Plain loads (allocate feat in MALL for K2's re-read).  [exact R7 config]
// ---------------------------------------------------------------------------
__global__ __launch_bounds__(256) void gn_partial(
    const float* __restrict__ feat,
    const int*   __restrict__ map,
    const int*   __restrict__ segstart,
    float*       __restrict__ PPART,
    int n_nodes, int rpb)
{
    const int lb = logical_block(blockIdx.x, gridDim.x);
    const int rs = lb * rpb;
    if (rs >= n_nodes) return;
    const int re = min(rs + rpb, n_nodes);

    const int tid = threadIdx.x;
    const int q = tid & (FEAT4 - 1);
    const int r = tid >> 7;

    __shared__ float4 lsum[2][FEAT4];
    __shared__ float4 lssq[2][FEAT4];
    const float4* __restrict__ f4 = (const float4*)feat;
    float4* __restrict__ P4 = (float4*)PPART;

    int cur = rs;
    int g = map[rs];
    int slot = lb - segstart[g] / rpb;
    while (cur < re) {
        const int send = min(segstart[g + 1], re);

        float4 sum = make_float4(0.f, 0.f, 0.f, 0.f);
        float4 ssq = make_float4(0.f, 0.f, 0.f, 0.f);
        #pragma unroll 4
        for (int row = cur + r; row < send; row += 2) {
            float4 v = f4[(size_t)row * FEAT4 + q];
            acc4(sum, v);
            accsq4(ssq, v);
        }
        lsum[r][q] = sum;
        lssq[r][q] = ssq;
        __syncthreads();
        if (r == 0 && slot >= 0 && slot < MAXSLOT) {
            const size_t o = ((size_t)(g * MAXSLOT + slot) * 2) * FEAT4 + q;
            P4[o]         = add4(lsum[0][q], lsum[1][q]);
            P4[o + FEAT4] = add4(lssq[0][q], lssq[1][q]);
        }
        __syncthreads();
        cur = send;
        if (cur < re) g = map[cur];
        slot = 0;   // later segments start inside this window
    }
}

// ---------------------------------------------------------------------------
// K2: fused finalize + apply — exact R7 config (NT loads, NT stores,
// unroll 4), plus ONE experimental change: REVERSED slab order.
// K1 reads slabs 0->2047; reversed K2 reads MRU-first, so any MALL
// residency of feat across the kernel boundary shows up as a win.
//   var(h-a*mu) = E[h^2] - mu^2*(2a-a^2); s = gamma/(sqrt(var)+eps);
//   t = beta - a*mu*s;  out = h*s + t.
// ---------------------------------------------------------------------------
__global__ __launch_bounds__(256) void gn_apply(
    const float* __restrict__ feat,
    const int*   __restrict__ map,
    const int*   __restrict__ segstart,
    const float* __restrict__ PPART,
    const float* __restrict__ alpha,
    const float* __restrict__ beta,
    const float* __restrict__ gamma,
    float*       __restrict__ out,
    int n_nodes, int rpb)
{
    const int lb = (gridDim.x - 1) - logical_block(blockIdx.x, gridDim.x);
    const int rs = lb * rpb;
    if (rs >= n_nodes) return;
    const int re = min(rs + rpb, n_nodes);

    const int tid = threadIdx.x;
    const int q = tid & (FEAT4 - 1);
    const int r = tid >> 7;

    const f32x4* __restrict__ f4n = (const f32x4*)feat;
    const float4* __restrict__ P4 = (const float4*)PPART;
    f32x4* __restrict__ o4 = (f32x4*)out;

    const float4 al = ((const float4*)alpha)[q];
    const float4 be = ((const float4*)beta)[q];
    const float4 ga = ((const float4*)gamma)[q];

    int cur = rs;
    int g = map[rs];
    while (cur < re) {
        const int gstart = segstart[g];
        const int gend   = segstart[g + 1];
        const int send   = min(gend, re);
        const int cnt    = gend - gstart;
        const int bfirst = gstart / rpb;
        int nslots = (gend - 1) / rpb - bfirst + 1;
        if (nslots > MAXSLOT) nslots = MAXSLOT;

        float4 sum = make_float4(0.f, 0.f, 0.f, 0.f);
        float4 ssq = make_float4(0.f, 0.f, 0.f, 0.f);
        for (int s = 0; s < nslots; ++s) {
            const size_t o = ((size_t)(g * MAXSLOT + s) * 2) * FEAT4 + q;
            acc4(sum, P4[o]);
            acc4(ssq, P4[o + FEAT4]);
        }

        const float inv = 1.0f / (float)max(cnt, 1);
        f32x4 sv, tv;
        {
            const float mu[4]  = { sum.x * inv, sum.y * inv, sum.z * inv, sum.w * inv };
            const float msq[4] = { ssq.x * inv, ssq.y * inv, ssq.z * inv, ssq.w * inv };
            const float aa[4]  = { al.x, al.y, al.z, al.w };
            const float bb[4]  = { be.x, be.y, be.z, be.w };
            const float gg[4]  = { ga.x, ga.y, ga.z, ga.w };
            #pragma unroll
            for (int j = 0; j < 4; ++j) {
                float var = msq[j] - mu[j] * mu[j] * (2.0f * aa[j] - aa[j] * aa[j]);
                var = fmaxf(var, 0.0f);
                const float s = gg[j] / (sqrtf(var) + EPS);
                sv[j] = s;
                tv[j] = bb[j] - aa[j] * mu[j] * s;
            }
        }

        #pragma unroll 4
        for (int row = cur + r; row < send; row += 2) {
            const size_t idx = (size_t)row * FEAT4 + q;
            f32x4 v = __builtin_nontemporal_load(&f4n[idx]);
            f32x4 o = v * sv + tv;
            __builtin_nontemporal_store(o, &o4[idx]);
        }
        cur = send;
        if (cur < re) g = map[cur];
    }
}

// ---------------------------------------------------------------------------
// Small-workspace fallback (R1 proven path; needs only ~2 MB).
// ---------------------------------------------------------------------------
__global__ __launch_bounds__(512) void graphnorm_stats(
    const float* __restrict__ feat,
    const int*   __restrict__ map,
    const float* __restrict__ alpha,
    const float* __restrict__ beta,
    const float* __restrict__ gamma,
    float* __restrict__ S,
    float* __restrict__ T,
    int n_nodes)
{
    const int g = blockIdx.x;
    int lo = 0, hi = n_nodes;
    while (lo < hi) { int mid = (lo + hi) >> 1; if (map[mid] < g) lo = mid + 1; else hi = mid; }
    const int seg_start = lo;
    hi = n_nodes;
    while (lo < hi) { int mid = (lo + hi) >> 1; if (map[mid] < g + 1) lo = mid + 1; else hi = mid; }
    const int seg_end = lo;
    const int cnt = seg_end - seg_start;

    const int tid = threadIdx.x;
    const int q = tid & (FEAT4 - 1);
    const int r = tid >> 7;

    float4 sum = make_float4(0.f, 0.f, 0.f, 0.f);
    float4 ssq = make_float4(0.f, 0.f, 0.f, 0.f);
    const float4* __restrict__ f4 = (const float4*)feat;

    for (int row = seg_start + r; row < seg_end; row += 4) {
        float4 v = f4[(size_t)row * FEAT4 + q];
        acc4(sum, v);
        accsq4(ssq, v);
    }

    __shared__ float4 lsum[4][FEAT4];
    __shared__ float4 lssq[4][FEAT4];
    lsum[r][q] = sum;
    lssq[r][q] = ssq;
    __syncthreads();

    if (r == 0) {
        #pragma unroll
        for (int k = 1; k < 4; ++k) {
            acc4(sum, lsum[k][q]);
            acc4(ssq, lssq[k][q]);
        }
        const float inv = 1.0f / (float)max(cnt, 1);
        float4 al = ((const float4*)alpha)[q];
        float4 be = ((const float4*)beta)[q];
        float4 ga = ((const float4*)gamma)[q];
        float mu[4]  = { sum.x * inv, sum.y * inv, sum.z * inv, sum.w * inv };
        float msq[4] = { ssq.x * inv, ssq.y * inv, ssq.z * inv, ssq.w * inv };
        float a[4]   = { al.x, al.y, al.z, al.w };
        float bb[4]  = { be.x, be.y, be.z, be.w };
        float gg[4]  = { ga.x, ga.y, ga.z, ga.w };
        float so[4], to[4];
        #pragma unroll
        for (int j = 0; j < 4; ++j) {
            float var = msq[j] - mu[j] * mu[j] * (2.0f * a[j] - a[j] * a[j]);
            var = fmaxf(var, 0.0f);
            float s = gg[j] / (sqrtf(var) + EPS);
            so[j] = s;
            to[j] = bb[j] - a[j] * mu[j] * s;
        }
        ((float4*)S)[(size_t)g * FEAT4 + q] = make_float4(so[0], so[1], so[2], so[3]);
        ((float4*)T)[(size_t)g * FEAT4 + q] = make_float4(to[0], to[1], to[2], to[3]);
    }
}

__global__ __launch_bounds__(256) void graphnorm_apply_tab(
    const float* __restrict__ feat,
    const int*   __restrict__ map,
    const float* __restrict__ S,
    const float* __restrict__ T,
    float* __restrict__ out,
    long total4)
{
    const float4* __restrict__ f4 = (const float4*)feat;
    const float4* __restrict__ S4 = (const float4*)S;
    const float4* __restrict__ T4 = (const float4*)T;
    f32x4* __restrict__ o4 = (f32x4*)out;

    const long stride = (long)gridDim.x * blockDim.x;
    for (long idx = (long)blockIdx.x * blockDim.x + threadIdx.x; idx < total4; idx += stride) {
        const int n = (int)(idx >> 7);
        const int q = (int)(idx & (FEAT4 - 1));
        const int g = map[n];
        float4 v = f4[idx];
        float4 s = S4[(size_t)g * FEAT4 + q];
        float4 t = T4[(size_t)g * FEAT4 + q];
        f32x4 o;
        o.x = v.x * s.x + t.x;
        o.y = v.y * s.y + t.y;
        o.z = v.z * s.z + t.z;
        o.w = v.w * s.w + t.w;
        o4[idx] = o;
    }
}

extern "C" void kernel_launch(void* const* d_in, const int* in_sizes, int n_in,
                              void* d_out, int out_size, void* d_ws, size_t ws_size,
                              hipStream_t stream) {
    const float* feat  = (const float*)d_in[0];
    const int*   map   = (const int*)d_in[1];
    const float* alpha = (const float*)d_in[2];
    const float* beta  = (const float*)d_in[3];
    const float* gamma = (const float*)d_in[4];

    const int n_nodes = in_sizes[1];
    const int rpb = (n_nodes + NB - 1) / NB;

    const size_t ppartElems = (size_t)NGRAPH * MAXSLOT * 2 * FEAT;   // 4.19M floats
    const size_t needBytes  = ppartElems * 4 + (NGRAPH + 1) * sizeof(int); // ~16.8 MB

    if (ws_size >= needBytes) {
        float* PPART    = (float*)d_ws;
        int*   SEGSTART = (int*)((float*)d_ws + ppartElems);

        const int bblocks = (n_nodes + 255) / 256;
        gn_bounds<<<bblocks, 256, 0, stream>>>(map, SEGSTART, n_nodes);
        gn_partial<<<NB, 256, 0, stream>>>(feat, map, SEGSTART, PPART, n_nodes, rpb);
        gn_apply<<<NB, 256, 0, stream>>>(feat, map, SEGSTART, PPART,
                                         alpha, beta, gamma,
                                         (float*)d_out, n_nodes, rpb);
    } else {
        float* S = (float*)d_ws;
        float* T = S + (size_t)NGRAPH * FEAT;
        graphnorm_stats<<<NGRAPH, 512, 0, stream>>>(feat, map, alpha, beta, gamma, S, T, n_nodes);
        const long total4 = (long)n_nodes * FEAT4;
        graphnorm_apply_tab<<<2048, 256, 0, stream>>>(feat, map, S, T, (float*)d_out, total4);
    }
}

// Round 11
// 111.150 us; speedup vs baseline: 2.6889x; 1.0313x over previous
//
#include <hip/hip_runtime.h>

#define FEAT 512
#define FEAT4 128          // FEAT / 4
#define NGRAPH 512
#define NB 2048            // row-partition blocks (rpb = 49 @ N=100000)
#define MAXSLOT 8          // max blocks one graph can span (cnt<=260 << 8*49)
#define EPS 1e-7f

typedef float f32x4 __attribute__((ext_vector_type(4)));

__device__ __forceinline__ void acc4(float4& s, const float4 v) {
    s.x += v.x; s.y += v.y; s.z += v.z; s.w += v.w;
}
__device__ __forceinline__ void accsq4(float4& s, const float4 v) {
    s.x += v.x * v.x; s.y += v.y * v.y; s.z += v.z * v.z; s.w += v.w * v.w;
}
__device__ __forceinline__ float4 add4(const float4 a, const float4 b) {
    return make_float4(a.x + b.x, a.y + b.y, a.z + b.z, a.w + b.w);
}
// XCD-chunked bijection (nb % 8 == 0): row-neighbor blocks share an XCD L2.
__device__ __forceinline__ int logical_block(int pb, int nb) {
    return (pb & 7) * (nb >> 3) + (pb >> 3);
}

// ---------------------------------------------------------------------------
// K0: segment-boundary table. SEGSTART[g] = lower_bound(map, g); SEGSTART[G]=n.
// Replaces per-block binary searches with O(1) L2-resident lookups.
// ---------------------------------------------------------------------------
__global__ __launch_bounds__(256) void gn_bounds(
    const int* __restrict__ map, int* __restrict__ segstart, int n_nodes)
{
    const int i = blockIdx.x * blockDim.x + threadIdx.x;
    if (i >= n_nodes) return;
    const int cur  = map[i];
    const int prev = (i == 0) ? -1 : map[i - 1];
    for (int g = prev + 1; g <= cur; ++g) segstart[g] = i;
    if (i == n_nodes - 1)
        for (int g = cur + 1; g <= NGRAPH; ++g) segstart[g] = n_nodes;
}

// ---------------------------------------------------------------------------
// K1: uniform row partition -> per-(graph, slot) raw moments.
// Block lb owns rows [lb*rpb,(lb+1)*rpb). Per segment: q = float4 column,
// r = row parity; LDS-reduce the two parities; write PPART[g][slot].
// Plain loads. [R7 config — best measured: 111.3 us total]
// ---------------------------------------------------------------------------
__global__ __launch_bounds__(256) void gn_partial(
    const float* __restrict__ feat,
    const int*   __restrict__ map,
    const int*   __restrict__ segstart,
    float*       __restrict__ PPART,
    int n_nodes, int rpb)
{
    const int lb = logical_block(blockIdx.x, gridDim.x);
    const int rs = lb * rpb;
    if (rs >= n_nodes) return;
    const int re = min(rs + rpb, n_nodes);

    const int tid = threadIdx.x;
    const int q = tid & (FEAT4 - 1);
    const int r = tid >> 7;

    __shared__ float4 lsum[2][FEAT4];
    __shared__ float4 lssq[2][FEAT4];
    const float4* __restrict__ f4 = (const float4*)feat;
    float4* __restrict__ P4 = (float4*)PPART;

    int cur = rs;
    int g = map[rs];
    int slot = lb - segstart[g] / rpb;
    while (cur < re) {
        const int send = min(segstart[g + 1], re);

        float4 sum = make_float4(0.f, 0.f, 0.f, 0.f);
        float4 ssq = make_float4(0.f, 0.f, 0.f, 0.f);
        #pragma unroll 4
        for (int row = cur + r; row < send; row += 2) {
            float4 v = f4[(size_t)row * FEAT4 + q];
            acc4(sum, v);
            accsq4(ssq, v);
        }
        lsum[r][q] = sum;
        lssq[r][q] = ssq;
        __syncthreads();
        if (r == 0 && slot >= 0 && slot < MAXSLOT) {
            const size_t o = ((size_t)(g * MAXSLOT + slot) * 2) * FEAT4 + q;
            P4[o]         = add4(lsum[0][q], lsum[1][q]);
            P4[o + FEAT4] = add4(lssq[0][q], lssq[1][q]);
        }
        __syncthreads();
        cur = send;
        if (cur < re) g = map[cur];
        slot = 0;   // later segments start inside this window
    }
}

// ---------------------------------------------------------------------------
// K2: fused finalize + apply (forward order — R7 exact config).
// Per segment: gather <=MAXSLOT partials (L2-hot), finalize s,t in regs:
//   var(h-a*mu) = E[h^2] - mu^2*(2a-a^2); s = gamma/(sqrt(var)+eps);
//   t = beta - a*mu*s;  out = h*s + t.
// NT loads + NT stores: R9's A/B showed plain stores cost ~12 us (write-
// allocate evicts useful lines); NT keeps both streams out of the caches.
// ---------------------------------------------------------------------------
__global__ __launch_bounds__(256) void gn_apply(
    const float* __restrict__ feat,
    const int*   __restrict__ map,
    const int*   __restrict__ segstart,
    const float* __restrict__ PPART,
    const float* __restrict__ alpha,
    const float* __restrict__ beta,
    const float* __restrict__ gamma,
    float*       __restrict__ out,
    int n_nodes, int rpb)
{
    const int lb = logical_block(blockIdx.x, gridDim.x);
    const int rs = lb * rpb;
    if (rs >= n_nodes) return;
    const int re = min(rs + rpb, n_nodes);

    const int tid = threadIdx.x;
    const int q = tid & (FEAT4 - 1);
    const int r = tid >> 7;

    const f32x4* __restrict__ f4n = (const f32x4*)feat;
    const float4* __restrict__ P4 = (const float4*)PPART;
    f32x4* __restrict__ o4 = (f32x4*)out;

    const float4 al = ((const float4*)alpha)[q];
    const float4 be = ((const float4*)beta)[q];
    const float4 ga = ((const float4*)gamma)[q];

    int cur = rs;
    int g = map[rs];
    while (cur < re) {
        const int gstart = segstart[g];
        const int gend   = segstart[g + 1];
        const int send   = min(gend, re);
        const int cnt    = gend - gstart;
        const int bfirst = gstart / rpb;
        int nslots = (gend - 1) / rpb - bfirst + 1;
        if (nslots > MAXSLOT) nslots = MAXSLOT;

        float4 sum = make_float4(0.f, 0.f, 0.f, 0.f);
        float4 ssq = make_float4(0.f, 0.f, 0.f, 0.f);
        for (int s = 0; s < nslots; ++s) {
            const size_t o = ((size_t)(g * MAXSLOT + s) * 2) * FEAT4 + q;
            acc4(sum, P4[o]);
            acc4(ssq, P4[o + FEAT4]);
        }

        const float inv = 1.0f / (float)max(cnt, 1);
        f32x4 sv, tv;
        {
            const float mu[4]  = { sum.x * inv, sum.y * inv, sum.z * inv, sum.w * inv };
            const float msq[4] = { ssq.x * inv, ssq.y * inv, ssq.z * inv, ssq.w * inv };
            const float aa[4]  = { al.x, al.y, al.z, al.w };
            const float bb[4]  = { be.x, be.y, be.z, be.w };
            const float gg[4]  = { ga.x, ga.y, ga.z, ga.w };
            #pragma unroll
            for (int j = 0; j < 4; ++j) {
                float var = msq[j] - mu[j] * mu[j] * (2.0f * aa[j] - aa[j] * aa[j]);
                var = fmaxf(var, 0.0f);
                const float s = gg[j] / (sqrtf(var) + EPS);
                sv[j] = s;
                tv[j] = bb[j] - aa[j] * mu[j] * s;
            }
        }

        #pragma unroll 4
        for (int row = cur + r; row < send; row += 2) {
            const size_t idx = (size_t)row * FEAT4 + q;
            f32x4 v = __builtin_nontemporal_load(&f4n[idx]);
            f32x4 o = v * sv + tv;
            __builtin_nontemporal_store(o, &o4[idx]);
        }
        cur = send;
        if (cur < re) g = map[cur];
    }
}

// ---------------------------------------------------------------------------
// Small-workspace fallback (R1 proven path; needs only ~2 MB).
// ---------------------------------------------------------------------------
__global__ __launch_bounds__(512) void graphnorm_stats(
    const float* __restrict__ feat,
    const int*   __restrict__ map,
    const float* __restrict__ alpha,
    const float* __restrict__ beta,
    const float* __restrict__ gamma,
    float* __restrict__ S,
    float* __restrict__ T,
    int n_nodes)
{
    const int g = blockIdx.x;
    int lo = 0, hi = n_nodes;
    while (lo < hi) { int mid = (lo + hi) >> 1; if (map[mid] < g) lo = mid + 1; else hi = mid; }
    const int seg_start = lo;
    hi = n_nodes;
    while (lo < hi) { int mid = (lo + hi) >> 1; if (map[mid] < g + 1) lo = mid + 1; else hi = mid; }
    const int seg_end = lo;
    const int cnt = seg_end - seg_start;

    const int tid = threadIdx.x;
    const int q = tid & (FEAT4 - 1);
    const int r = tid >> 7;

    float4 sum = make_float4(0.f, 0.f, 0.f, 0.f);
    float4 ssq = make_float4(0.f, 0.f, 0.f, 0.f);
    const float4* __restrict__ f4 = (const float4*)feat;

    for (int row = seg_start + r; row < seg_end; row += 4) {
        float4 v = f4[(size_t)row * FEAT4 + q];
        acc4(sum, v);
        accsq4(ssq, v);
    }

    __shared__ float4 lsum[4][FEAT4];
    __shared__ float4 lssq[4][FEAT4];
    lsum[r][q] = sum;
    lssq[r][q] = ssq;
    __syncthreads();

    if (r == 0) {
        #pragma unroll
        for (int k = 1; k < 4; ++k) {
            acc4(sum, lsum[k][q]);
            acc4(ssq, lssq[k][q]);
        }
        const float inv = 1.0f / (float)max(cnt, 1);
        float4 al = ((const float4*)alpha)[q];
        float4 be = ((const float4*)beta)[q];
        float4 ga = ((const float4*)gamma)[q];
        float mu[4]  = { sum.x * inv, sum.y * inv, sum.z * inv, sum.w * inv };
        float msq[4] = { ssq.x * inv, ssq.y * inv, ssq.z * inv, ssq.w * inv };
        float a[4]   = { al.x, al.y, al.z, al.w };
        float bb[4]  = { be.x, be.y, be.z, be.w };
        float gg[4]  = { ga.x, ga.y, ga.z, ga.w };
        float so[4], to[4];
        #pragma unroll
        for (int j = 0; j < 4; ++j) {
            float var = msq[j] - mu[j] * mu[j] * (2.0f * a[j] - a[j] * a[j]);
            var = fmaxf(var, 0.0f);
            float s = gg[j] / (sqrtf(var) + EPS);
            so[j] = s;
            to[j] = bb[j] - a[j] * mu[j] * s;
        }
        ((float4*)S)[(size_t)g * FEAT4 + q] = make_float4(so[0], so[1], so[2], so[3]);
        ((float4*)T)[(size_t)g * FEAT4 + q] = make_float4(to[0], to[1], to[2], to[3]);
    }
}

__global__ __launch_bounds__(256) void graphnorm_apply_tab(
    const float* __restrict__ feat,
    const int*   __restrict__ map,
    const float* __restrict__ S,
    const float* __restrict__ T,
    float* __restrict__ out,
    long total4)
{
    const float4* __restrict__ f4 = (const float4*)feat;
    const float4* __restrict__ S4 = (const float4*)S;
    const float4* __restrict__ T4 = (const float4*)T;
    f32x4* __restrict__ o4 = (f32x4*)out;

    const long stride = (long)gridDim.x * blockDim.x;
    for (long idx = (long)blockIdx.x * blockDim.x + threadIdx.x; idx < total4; idx += stride) {
        const int n = (int)(idx >> 7);
        const int q = (int)(idx & (FEAT4 - 1));
        const int g = map[n];
        float4 v = f4[idx];
        float4 s = S4[(size_t)g * FEAT4 + q];
        float4 t = T4[(size_t)g * FEAT4 + q];
        f32x4 o;
        o.x = v.x * s.x + t.x;
        o.y = v.y * s.y + t.y;
        o.z = v.z * s.z + t.z;
        o.w = v.w * s.w + t.w;
        o4[idx] = o;
    }
}

extern "C" void kernel_launch(void* const* d_in, const int* in_sizes, int n_in,
                              void* d_out, int out_size, void* d_ws, size_t ws_size,
                              hipStream_t stream) {
    const float* feat  = (const float*)d_in[0];
    const int*   map   = (const int*)d_in[1];
    const float* alpha = (const float*)d_in[2];
    const float* beta  = (const float*)d_in[3];
    const float* gamma = (const float*)d_in[4];

    const int n_nodes = in_sizes[1];
    const int rpb = (n_nodes + NB - 1) / NB;

    const size_t ppartElems = (size_t)NGRAPH * MAXSLOT * 2 * FEAT;   // 4.19M floats
    const size_t needBytes  = ppartElems * 4 + (NGRAPH + 1) * sizeof(int); // ~16.8 MB

    if (ws_size >= needBytes) {
        float* PPART    = (float*)d_ws;
        int*   SEGSTART = (int*)((float*)d_ws + ppartElems);

        const int bblocks = (n_nodes + 255) / 256;
        gn_bounds<<<bblocks, 256, 0, stream>>>(map, SEGSTART, n_nodes);
        gn_partial<<<NB, 256, 0, stream>>>(feat, map, SEGSTART, PPART, n_nodes, rpb);
        gn_apply<<<NB, 256, 0, stream>>>(feat, map, SEGSTART, PPART,
                                         alpha, beta, gamma,
                                         (float*)d_out, n_nodes, rpb);
    } else {
        float* S = (float*)d_ws;
        float* T = S + (size_t)NGRAPH * FEAT;
        graphnorm_stats<<<NGRAPH, 512, 0, stream>>>(feat, map, alpha, beta, gamma, S, T, n_nodes);
        const long total4 = (long)n_nodes * FEAT4;
        graphnorm_apply_tab<<<2048, 256, 0, stream>>>(feat, map, S, T, (float*)d_out, total4);
    }
}